// Round 7
// baseline (572.800 us; speedup 1.0000x reference)
//
#include <hip/hip_runtime.h>
#include <hip/hip_bf16.h>
#include <stdint.h>
#include <stddef.h>

typedef __attribute__((ext_vector_type(8))) short short8;
typedef __attribute__((ext_vector_type(4))) float floatx4;

#define GLDS16(gptr, lptr)                                                         \
  __builtin_amdgcn_global_load_lds(                                                \
      (const __attribute__((address_space(1))) void*)(gptr),                       \
      (__attribute__((address_space(3))) void*)(lptr), 16, 0, 0)

#define MTOT  100352   // 2048*49 tokens, = 784*128
#define KDIM  384
#define NQKV  1152
#define NPROJ 384

static __device__ __forceinline__ unsigned int bfu(float f) {
    __hip_bfloat16 h = __float2bfloat16(f);
    return (unsigned int)*(unsigned short*)&h;
}

// ---------------------------------------------------------------------------
// merged fp32->bf16 convert: x (9,633,792 float4s) then wq (110,592) then
// wp (36,864).  Total 9,781,248 float4s = exactly 38208 blocks x 256.
// Same per-element RNE rounding as before -> identical numerics; 3 launches
// collapsed into 1.
// ---------------------------------------------------------------------------
__global__ void cvt_all_kernel(const float* __restrict__ x,
                               const float* __restrict__ wq,
                               const float* __restrict__ wp,
                               __hip_bfloat16* __restrict__ xo,
                               __hip_bfloat16* __restrict__ wqo,
                               __hip_bfloat16* __restrict__ wpo) {
    int i = blockIdx.x * 256 + threadIdx.x;
    const float* src;
    __hip_bfloat16* dst;
    int j;
    if (i < 9633792) {
        src = x; dst = xo; j = i;
    } else if (i < 9744384) {
        src = wq; dst = wqo; j = i - 9633792;
    } else {
        src = wp; dst = wpo; j = i - 9744384;
    }
    float4 v = ((const float4*)src)[j];
    uint2 p;
    p.x = bfu(v.x) | (bfu(v.y) << 16);
    p.y = bfu(v.z) | (bfu(v.w) << 16);
    *(uint2*)(dst + (size_t)j * 4) = p;
}

// ---------------------------------------------------------------------------
// comb[h][w][row(49)][52]: col<49 -> tbl+mask ; col>=49 -> -1e30
// ---------------------------------------------------------------------------
__global__ void build_bias_kernel(const float* __restrict__ tbl,
                                  const float* __restrict__ mask,
                                  float* __restrict__ comb) {
    int tid = blockIdx.x * 256 + threadIdx.x;
    if (tid >= 12 * 64 * 49 * 52) return;
    int hw = tid / 2548;
    int nm = tid - hw * 2548;
    int row = nm / 52;
    int col = nm - row * 52;
    int h = hw >> 6;
    int w2 = hw & 63;
    float v = -1e30f;
    if (col < 49) {
        int i1 = row / 7, j1 = row - i1 * 7;
        int i2 = col / 7, j2 = col - i2 * 7;
        int ridx = (i1 - i2 + 6) * 13 + (j1 - j2 + 6);
        v = tbl[ridx * 12 + h] + mask[(size_t)w2 * 2401 + row * 49 + col];
    }
    comb[tid] = v;
}

// ---------------------------------------------------------------------------
// C = A(MxK) * B(NxK)^T + bias.  128x128 tile, BK=64, XOR col-swizzled LDS.
// ROUND-0 PROVEN STRUCTURE, restored verbatim (best measured: 134.7-140 us).
// Rounds 1/3/5 showed: deep pipeline @1 blk/CU, BM=256 @2 blk/CU, and fused
// f32-A @3 blk/CU ALL regress — cross-block TLP at 4 blocks/CU is what hides
// the vmcnt(0) barrier drain at NT=6.  Do not touch this kernel again.
// Operand-SWAPPED MFMA: acc[i][j] holds C^T tile -> lane l15 = M-row (token),
// quad*4+r = 4 consecutive N-cols -> vectorized epilogue stores.
// EPI==0: bf16 out (q cols scaled by 1/sqrt(32)), uint2 (4xbf16) stores.
// EPI==1: fp32 out, float4 stores.
// ---------------------------------------------------------------------------
template <int EPI>
__global__ __launch_bounds__(256, 4) void gemm_bt_kernel(
    const __hip_bfloat16* __restrict__ A, const __hip_bfloat16* __restrict__ B,
    const float* __restrict__ bias, float* __restrict__ Cout,
    __hip_bfloat16* __restrict__ Cbf, int N, int NBN) {
    __shared__ __hip_bfloat16 sA[128 * 64];
    __shared__ __hip_bfloat16 sB[128 * 64];
    const int t = threadIdx.x;
    const int per_chunk = 16 * NBN;
    const int chunk = blockIdx.x / per_chunk;
    const int rr = blockIdx.x - chunk * per_chunk;
    const int bn = rr >> 4;
    const int bm = chunk * 16 + (rr & 15);

    const int lane = t & 63;
    const int w = t >> 6;
    const int wm = w & 1, wn = w >> 1;
    const int quad = lane >> 4, l15 = lane & 15;
    const int srow = t >> 3;                 // 0..31
    const int scg = t & 7;                   // LDS col-group
    const int sg = scg ^ (srow & 7);         // swizzled global col-group
    const int rsw = l15 & 7;                 // read-side swizzle

    const __hip_bfloat16* Ab = A + (size_t)bm * 128 * KDIM;
    const __hip_bfloat16* Bb = B + (size_t)bn * 128 * KDIM;

    const floatx4 fzero = {0.f, 0.f, 0.f, 0.f};
    floatx4 acc[4][4];
#pragma unroll
    for (int i = 0; i < 4; ++i)
#pragma unroll
        for (int j = 0; j < 4; ++j) acc[i][j] = fzero;

    for (int kk = 0; kk < KDIM; kk += 64) {
#pragma unroll
        for (int i = 0; i < 4; ++i) {
            const int r0 = srow + i * 32;
            GLDS16(Ab + (size_t)r0 * KDIM + kk + sg * 8, &sA[r0 * 64 + scg * 8]);
            GLDS16(Bb + (size_t)r0 * KDIM + kk + sg * 8, &sB[r0 * 64 + scg * 8]);
        }
        __syncthreads();
#pragma unroll
        for (int kk2 = 0; kk2 < 2; ++kk2) {
            short8 af[4], bf[4];
#pragma unroll
            for (int i = 0; i < 4; ++i)
                af[i] = *(const short8*)&sA[(wm * 64 + i * 16 + l15) * 64 +
                                            ((kk2 * 4 + quad) ^ rsw) * 8];
#pragma unroll
            for (int j = 0; j < 4; ++j)
                bf[j] = *(const short8*)&sB[(wn * 64 + j * 16 + l15) * 64 +
                                            ((kk2 * 4 + quad) ^ rsw) * 8];
#pragma unroll
            for (int i = 0; i < 4; ++i)
#pragma unroll
                for (int j = 0; j < 4; ++j)
                    acc[i][j] = __builtin_amdgcn_mfma_f32_16x16x32_bf16(
                        bf[j], af[i], acc[i][j], 0, 0, 0);  // SWAPPED
        }
        __syncthreads();
    }

    // epilogue: lane = token row m; quad*4 = first of 4 consecutive cols
    if (EPI == 0) {
        const float scale = 0.17677669529663687f;  // 1/sqrt(32)
#pragma unroll
        for (int i = 0; i < 4; ++i) {
            const int m = bm * 128 + wm * 64 + i * 16 + l15;
#pragma unroll
            for (int j = 0; j < 4; ++j) {
                const int f0 = bn * 128 + wn * 64 + j * 16 + quad * 4;
                const float4 bv = *(const float4*)&bias[f0];
                const float sc = (f0 < 384) ? scale : 1.0f;
                uint2 pk;
                pk.x = bfu((acc[i][j][0] + bv.x) * sc) |
                       (bfu((acc[i][j][1] + bv.y) * sc) << 16);
                pk.y = bfu((acc[i][j][2] + bv.z) * sc) |
                       (bfu((acc[i][j][3] + bv.w) * sc) << 16);
                *(uint2*)&Cbf[(size_t)m * NQKV + f0] = pk;
            }
        }
    } else {
#pragma unroll
        for (int i = 0; i < 4; ++i) {
            const int m = bm * 128 + wm * 64 + i * 16 + l15;
#pragma unroll
            for (int j = 0; j < 4; ++j) {
                const int f0 = bn * 128 + wn * 64 + j * 16 + quad * 4;
                const float4 bv = *(const float4*)&bias[f0];
                float4 o;
                o.x = acc[i][j][0] + bv.x;
                o.y = acc[i][j][1] + bv.y;
                o.z = acc[i][j][2] + bv.z;
                o.w = acc[i][j][3] + bv.w;
                *(float4*)&Cout[(size_t)m * N + f0] = o;
            }
        }
    }
}

// ---------------------------------------------------------------------------
// attention, one wave per (b_, h).  Reads q/k/v from row-major qkv (M x 1152).
// S^T = K*Q^T so softmax rows live in-lane.  V transposed via blocked LDS.
// ROUND-6 OCCUPANCY SURGERY (structure & numerics identical):
//   - per-im softmax: only ST[4] (16 VGPR) live instead of ST[4][4] (64);
//   - per-im PV + immediate store: only 2 aP + 1 O tile live (was 32+32);
//     est. peak VGPR ~150 -> <128, lifting the m69 8-waves/CU register cap
//     to the 16-wave class;
//   - sP shrunk 64 -> 49 rows (writes guarded m<49; aP reads row-clamped to
//     48 — clamped rows feed only outputs discarded at the m<49 store guard);
//     LDS 13.4 KB -> 11.3 KB: 12 -> 14 blocks/CU.
//   MFMAs stay unconditional (wave ops outside divergent branches).
// ---------------------------------------------------------------------------
__global__ __launch_bounds__(64) void attn_kernel(
    const __hip_bfloat16* __restrict__ qkv,
    const float* __restrict__ comb,
    __hip_bfloat16* __restrict__ attn_out) {
    __shared__ unsigned short sP[49 * 72];    // 7056 B
    __shared__ unsigned short sVB[4][66][8];  // 4224 B  [d>>3][n][d&7]
    const int id = blockIdx.x;
    const int h = id >> 11;
    const int rem = id & 2047;
    const int w = rem >> 5;
    const int b = rem & 31;
    const int b_ = b * 64 + w;
    const int lane = threadIdx.x;
    const int quad = lane >> 4, l15 = lane & 15;
    const short* base = (const short*)qkv + (size_t)b_ * 49 * 1152 + h * 32;

    const floatx4 fzero = {0.f, 0.f, 0.f, 0.f};

    short8 bQ[4], aK[4];
#pragma unroll
    for (int im = 0; im < 4; ++im) {
        int m = im * 16 + l15;
        m = m > 48 ? 48 : m;
        bQ[im] = *(const short8*)(base + (size_t)m * 1152 + quad * 8);
    }
#pragma unroll
    for (int jn = 0; jn < 4; ++jn) {
        int n = jn * 16 + l15;
        n = n > 48 ? 48 : n;
        aK[jn] = *(const short8*)(base + (size_t)n * 1152 + 384 + quad * 8);
    }
    // V rows -> blocked LDS (zero the pad rows to avoid NaN garbage)
    const short8 zero8 = {0, 0, 0, 0, 0, 0, 0, 0};
#pragma unroll
    for (int jn = 0; jn < 4; ++jn) {
        const int n = jn * 16 + l15;
        const int nc = n > 48 ? 48 : n;
        short8 vv = *(const short8*)(base + (size_t)nc * 1152 + 768 + quad * 8);
        if (n > 48) vv = zero8;
        *(short8*)&sVB[quad][n][0] = vv;
    }

    const float* cb = comb + (size_t)(h * 64 + w) * 2548;
    // QK^T + softmax per im-slice: ST[jn][r] = S[m=im*16+l15][n=jn*16+quad*4+r]
#pragma unroll
    for (int im = 0; im < 4; ++im) {
        floatx4 ST[4];
#pragma unroll
        for (int jn = 0; jn < 4; ++jn)
            ST[jn] = __builtin_amdgcn_mfma_f32_16x16x32_bf16(aK[jn], bQ[im],
                                                             fzero, 0, 0, 0);
        const int m = im * 16 + l15;
        const int mrow = m > 48 ? 48 : m;
        const float* rp = cb + mrow * 52;
        float v[16];
#pragma unroll
        for (int jn = 0; jn < 3; ++jn) {
            float4 c4 = *(const float4*)(rp + jn * 16 + quad * 4);
            v[jn * 4 + 0] = ST[jn][0] + c4.x;
            v[jn * 4 + 1] = ST[jn][1] + c4.y;
            v[jn * 4 + 2] = ST[jn][2] + c4.z;
            v[jn * 4 + 3] = ST[jn][3] + c4.w;
        }
        {
            const float s48 = rp[48];
            v[12] = (quad == 0) ? (ST[3][0] + s48) : -1e30f;
            v[13] = -1e30f;
            v[14] = -1e30f;
            v[15] = -1e30f;
        }
        float mx = v[0];
#pragma unroll
        for (int q = 1; q < 16; ++q) mx = fmaxf(mx, v[q]);
        mx = fmaxf(mx, __shfl_xor(mx, 16));
        mx = fmaxf(mx, __shfl_xor(mx, 32));
        float sum = 0.f;
#pragma unroll
        for (int q = 0; q < 16; ++q) {
            v[q] = __expf(v[q] - mx);
            sum += v[q];
        }
        sum += __shfl_xor(sum, 16);
        sum += __shfl_xor(sum, 32);
        const float inv = 1.0f / sum;
        if (m < 49) {
#pragma unroll
            for (int jn = 0; jn < 4; ++jn) {
                uint2 pk;
                pk.x = bfu(v[jn * 4 + 0] * inv) |
                       (bfu(v[jn * 4 + 1] * inv) << 16);
                pk.y = bfu(v[jn * 4 + 2] * inv) |
                       (bfu(v[jn * 4 + 3] * inv) << 16);
                *(uint2*)&sP[m * 72 + jn * 16 + quad * 4] = pk;
            }
        }
    }
    __syncthreads();

    // V fragments from blocked LDS: bV[jd][kk][jj] = V[kk*32+quad*8+jj][jd*16+l15]
    short8 bV[2][2];
#pragma unroll
    for (int jd = 0; jd < 2; ++jd) {
        const int d = jd * 16 + l15;
        const int db = d >> 3, dl = d & 7;
#pragma unroll
        for (int kk = 0; kk < 2; ++kk) {
            short8 tmp;
#pragma unroll
            for (int jj = 0; jj < 8; ++jj)
                tmp[jj] = (short)sVB[db][kk * 32 + quad * 8 + jj][dl];
            bV[jd][kk] = tmp;
        }
    }

    // PV per im-slice, immediate store.  O^T tiles: row = d (quad*4+r
    // consecutive), col = token m = l15.
#pragma unroll
    for (int im = 0; im < 4; ++im) {
        const int m = im * 16 + l15;
        const int mr = m > 48 ? 48 : m;
        const short8 aP0 = *(const short8*)&sP[mr * 72 + quad * 8];
        const short8 aP1 = *(const short8*)&sP[mr * 72 + 32 + quad * 8];
#pragma unroll
        for (int jd = 0; jd < 2; ++jd) {
            floatx4 o = __builtin_amdgcn_mfma_f32_16x16x32_bf16(bV[jd][0], aP0,
                                                                fzero, 0, 0, 0);
            o = __builtin_amdgcn_mfma_f32_16x16x32_bf16(bV[jd][1], aP1, o, 0, 0,
                                                        0);
            if (m < 49) {
                uint2 pk;
                pk.x = bfu(o[0]) | (bfu(o[1]) << 16);
                pk.y = bfu(o[2]) | (bfu(o[3]) << 16);
                *(uint2*)&attn_out[((size_t)b_ * 49 + m) * 384 + h * 32 +
                                   jd * 16 + quad * 4] = pk;
            }
        }
    }
}

// ---------------------------------------------------------------------------
extern "C" void kernel_launch(void* const* d_in, const int* in_sizes, int n_in,
                              void* d_out, int out_size, void* d_ws,
                              size_t ws_size, hipStream_t stream) {
    (void)in_sizes; (void)n_in; (void)out_size; (void)ws_size;
    const float* x      = (const float*)d_in[0];
    const float* mask   = (const float*)d_in[1];
    const float* qkv_w  = (const float*)d_in[2];
    const float* qkv_b  = (const float*)d_in[3];
    const float* proj_w = (const float*)d_in[4];
    const float* proj_b = (const float*)d_in[5];
    const float* tbl    = (const float*)d_in[6];
    float* out = (float*)d_out;
    char* ws = (char*)d_ws;

    // layout (bytes), total 316,403,712:
    //   [0, 77070336)          x_bf / attn_out (aliased; x_bf dead after qkv)
    //   [77070336, 84897792)   comb (7,827,456); wq_bf (884,736) aliased at
    //                          start — wq dead (qkv GEMM done) before comb
    //                          is built
    //   [84897792, 85192704)   wp_bf (294,912)
    //   [85192704, 316403712)  qkv_out row-major M x 1152 bf16 (231,211,008)
    __hip_bfloat16* x_bf   = (__hip_bfloat16*)(ws);
    __hip_bfloat16* wq_bf  = (__hip_bfloat16*)(ws + 77070336);
    float*          comb   = (float*)(ws + 77070336);
    __hip_bfloat16* wp_bf  = (__hip_bfloat16*)(ws + 84897792);
    __hip_bfloat16* qkv_o  = (__hip_bfloat16*)(ws + 85192704);
    __hip_bfloat16* attn_o = x_bf;

    // one merged convert dispatch (x + wq + wp), exactly 38208 x 256 threads
    cvt_all_kernel<<<38208, 256, 0, stream>>>(x, qkv_w, proj_w, x_bf, wq_bf,
                                              wp_bf);
    gemm_bt_kernel<0><<<784 * 9, 256, 0, stream>>>(x_bf, wq_bf, qkv_b, nullptr,
                                                   qkv_o, NQKV, 9);
    build_bias_kernel<<<(12 * 64 * 49 * 52 + 255) / 256, 256, 0, stream>>>(
        tbl, mask, comb);
    attn_kernel<<<2048 * 12, 64, 0, stream>>>(qkv_o, comb, attn_o);
    gemm_bt_kernel<1><<<784 * 3, 256, 0, stream>>>(attn_o, wp_bf, proj_b, out,
                                                   nullptr, NPROJ, 3);
}